// Round 1
// baseline (211.251 us; speedup 1.0000x reference)
//
#include <hip/hip_runtime.h>

#define BATCH 64
#define SEQ   512
#define JDIM  96
#define TN    64
#define KC    64

// ---------------- T1: xT[j][b*SEQ+m] = x[b][m][j]  (2D transpose [32768 x 96] -> [96 x 32768])
__global__ __launch_bounds__(256) void transpose_in_kernel(
    const float* __restrict__ x, float* __restrict__ xT) {
  __shared__ float tile[JDIM * 65];  // [j][rr], stride 65
  const int r0 = blockIdx.x * 64;    // 512 blocks cover R = 32768
  const int R = BATCH * SEQ;
  for (int idx = threadIdx.x; idx < 64 * JDIM; idx += 256) {
    int rr = idx / JDIM, j = idx % JDIM;              // j fastest -> coalesced read
    tile[j * 65 + rr] = x[(size_t)(r0 + rr) * JDIM + j];
  }
  __syncthreads();
  for (int idx = threadIdx.x; idx < 64 * JDIM; idx += 256) {
    int j = idx / 64, rr = idx % 64;                  // rr fastest -> coalesced write
    xT[(size_t)j * R + r0 + rr] = tile[j * 65 + rr];
  }
}

// ---------------- Fused: per block (j, n-tile of 64): C[64b x 64n] = X_j * exp(pre+off)^T, then /L
__global__ __launch_bounds__(256, 4) void fused_kernel(
    const float* __restrict__ xT,    // [J][B][SEQ]
    const float* __restrict__ off,   // [J][SEQ][SEQ]
    const float* __restrict__ pre,   // [SEQ][SEQ]
    float* __restrict__ outT) {      // [J][SEQ][B]
  __shared__ float As[BATCH * 65];   // [b][k]   stride 65 (scalar reads, 2-way = free)
  __shared__ float Bs[KC * 68];      // [m][n]   stride 68 (aligned float4 reads)
  __shared__ float Lred[TN * 17];
  __shared__ float Linv[TN];

  const int j  = blockIdx.x % JDIM;
  const int n0 = (blockIdx.x / JDIM) * TN;

  const int tid = threadIdx.x;
  const int tx = tid & 15;   // 0..15
  const int ty = tid >> 4;   // 0..15

  float Lpart[4] = {0.f, 0.f, 0.f, 0.f};
  float acc[4][4];
#pragma unroll
  for (int i = 0; i < 4; ++i)
#pragma unroll
    for (int q = 0; q < 4; ++q) acc[i][q] = 0.f;

  const float* xTj  = xT  + (size_t)j * (BATCH * SEQ);
  const float* offj = off + (size_t)j * (SEQ * SEQ);

  for (int ch = 0; ch < SEQ / KC; ++ch) {
    const int m0 = ch * KC;
    // stage A: As[b][ml] = xT[j][b][m0+ml]   (coalesced float4 global read)
#pragma unroll
    for (int it = 0; it < 4; ++it) {
      const int b = ty + 16 * it;
      float4 v = *(const float4*)(xTj + (size_t)b * SEQ + m0 + 4 * tx);
      const int base = b * 65 + 4 * tx;
      As[base + 0] = v.x; As[base + 1] = v.y; As[base + 2] = v.z; As[base + 3] = v.w;
    }
    // stage B: Bs[ml][nl] = exp(off+pre); accumulate row-sum partials in registers
#pragma unroll
    for (int it = 0; it < 4; ++it) {
      const int nl = ty + 16 * it;
      const int n  = n0 + nl;
      float4 o = *(const float4*)(offj + (size_t)n * SEQ + m0 + 4 * tx);
      float4 p = *(const float4*)(pre  + (size_t)n * SEQ + m0 + 4 * tx);
      const float e0 = __expf(o.x + p.x);
      const float e1 = __expf(o.y + p.y);
      const float e2 = __expf(o.z + p.z);
      const float e3 = __expf(o.w + p.w);
      const int ml = 4 * tx;
      Bs[(ml + 0) * 68 + nl] = e0;
      Bs[(ml + 1) * 68 + nl] = e1;
      Bs[(ml + 2) * 68 + nl] = e2;
      Bs[(ml + 3) * 68 + nl] = e3;
      Lpart[it] += (e0 + e1) + (e2 + e3);
    }
    __syncthreads();
    // GEMM: thread tile b = 4*tx..+3, n = 4*ty..+3
#pragma unroll 8
    for (int k = 0; k < KC; ++k) {
      const float4 bf = *(const float4*)&Bs[k * 68 + 4 * ty];
      const float a0 = As[(4 * tx + 0) * 65 + k];
      const float a1 = As[(4 * tx + 1) * 65 + k];
      const float a2 = As[(4 * tx + 2) * 65 + k];
      const float a3 = As[(4 * tx + 3) * 65 + k];
      acc[0][0] = fmaf(a0, bf.x, acc[0][0]);
      acc[0][1] = fmaf(a0, bf.y, acc[0][1]);
      acc[0][2] = fmaf(a0, bf.z, acc[0][2]);
      acc[0][3] = fmaf(a0, bf.w, acc[0][3]);
      acc[1][0] = fmaf(a1, bf.x, acc[1][0]);
      acc[1][1] = fmaf(a1, bf.y, acc[1][1]);
      acc[1][2] = fmaf(a1, bf.z, acc[1][2]);
      acc[1][3] = fmaf(a1, bf.w, acc[1][3]);
      acc[2][0] = fmaf(a2, bf.x, acc[2][0]);
      acc[2][1] = fmaf(a2, bf.y, acc[2][1]);
      acc[2][2] = fmaf(a2, bf.z, acc[2][2]);
      acc[2][3] = fmaf(a2, bf.w, acc[2][3]);
      acc[3][0] = fmaf(a3, bf.x, acc[3][0]);
      acc[3][1] = fmaf(a3, bf.y, acc[3][1]);
      acc[3][2] = fmaf(a3, bf.z, acc[3][2]);
      acc[3][3] = fmaf(a3, bf.w, acc[3][3]);
    }
    __syncthreads();
  }

  // reduce L across the 16 tx partials per row
#pragma unroll
  for (int it = 0; it < 4; ++it) Lred[(ty + 16 * it) * 17 + tx] = Lpart[it];
  __syncthreads();
  if (tid < TN) {
    float s = 0.f;
#pragma unroll
    for (int i = 0; i < 16; ++i) s += Lred[tid * 17 + i];
    Linv[tid] = 1.0f / s;
  }
  __syncthreads();

  // epilogue: outT[j][n][b], coalesced float4 along b
  float* outTj = outT + (size_t)j * (SEQ * BATCH);
#pragma unroll
  for (int q = 0; q < 4; ++q) {
    const int n = n0 + 4 * ty + q;
    const float linv = Linv[4 * ty + q];
    float4 v;
    v.x = acc[0][q] * linv;
    v.y = acc[1][q] * linv;
    v.z = acc[2][q] * linv;
    v.w = acc[3][q] * linv;
    *(float4*)(outTj + (size_t)n * BATCH + 4 * tx) = v;
  }
}

// ---------------- T2: out[b][n][j] = outT[j][n][b]  (per-n 96x64 transpose)
__global__ __launch_bounds__(256) void transpose_out_kernel(
    const float* __restrict__ outT, float* __restrict__ out) {
  __shared__ float tile[JDIM * 65];  // [j][b]
  const int n = blockIdx.x;          // 512 blocks
  for (int idx = threadIdx.x; idx < JDIM * BATCH; idx += 256) {
    int j = idx / BATCH, b = idx % BATCH;             // b fastest -> coalesced read
    tile[j * 65 + b] = outT[((size_t)j * SEQ + n) * BATCH + b];
  }
  __syncthreads();
  for (int idx = threadIdx.x; idx < JDIM * BATCH; idx += 256) {
    int b = idx / JDIM, j = idx % JDIM;               // j fastest -> coalesced write
    out[((size_t)b * SEQ + n) * JDIM + j] = tile[j * 65 + b];
  }
}

extern "C" void kernel_launch(void* const* d_in, const int* in_sizes, int n_in,
                              void* d_out, int out_size, void* d_ws, size_t ws_size,
                              hipStream_t stream) {
  const float* x   = (const float*)d_in[0];  // [64, 512, 96]
  const float* off = (const float*)d_in[1];  // [96, 512, 512]
  const float* pre = (const float*)d_in[2];  // [512, 512]
  float* out = (float*)d_out;                // [64, 512, 96]

  float* xT   = (float*)d_ws;                        // [96][64][512] = 12.58 MB
  float* outT = xT + (size_t)JDIM * BATCH * SEQ;     // [96][512][64] = 12.58 MB

  transpose_in_kernel<<<BATCH * SEQ / 64, 256, 0, stream>>>(x, xT);
  fused_kernel<<<JDIM * (SEQ / TN), 256, 0, stream>>>(xT, off, pre, outT);
  transpose_out_kernel<<<SEQ, 256, 0, stream>>>(outT, out);
}

// Round 2
// 178.220 us; speedup vs baseline: 1.1853x; 1.1853x over previous
//
#include <hip/hip_runtime.h>

#define BATCH 64
#define SEQ   512
#define JDIM  96
#define TN    64
#define KC    64
#define LDB   72   // bf16 row stride for As/Bs: 144 B, 16B-aligned, breaks pow2 banking

typedef __attribute__((ext_vector_type(8))) short bf16x8;
typedef __attribute__((ext_vector_type(4))) float f32x4;

// exact RNE float->bf16 (inputs are finite positive exps / normal floats)
__device__ __forceinline__ unsigned short f2bf(float f) {
  unsigned u = __float_as_uint(f);
  u += 0x7FFFu + ((u >> 16) & 1u);
  return (unsigned short)(u >> 16);
}

// ---------------- T1: xT[j][b*SEQ+m] = bf16(x[b][m][j])
__global__ __launch_bounds__(256) void transpose_in_kernel(
    const float* __restrict__ x, unsigned short* __restrict__ xT) {
  __shared__ float tile[JDIM * 65];
  const int r0 = blockIdx.x * 64;   // 512 blocks cover R = 32768 rows
  const int R = BATCH * SEQ;
  for (int idx = threadIdx.x; idx < 64 * JDIM; idx += 256) {
    int rr = idx / JDIM, j = idx - rr * JDIM;         // j fastest -> coalesced read
    tile[j * 65 + rr] = x[(size_t)(r0 + rr) * JDIM + j];
  }
  __syncthreads();
  for (int idx = threadIdx.x; idx < JDIM * 32; idx += 256) {
    int j = idx >> 5, rg = idx & 31;                  // rg fastest -> coalesced write
    float f0 = tile[j * 65 + 2 * rg];
    float f1 = tile[j * 65 + 2 * rg + 1];
    unsigned pk = (unsigned)f2bf(f0) | ((unsigned)f2bf(f1) << 16);
    *(unsigned*)(&xT[(size_t)j * R + r0 + 2 * rg]) = pk;
  }
}

// ---------------- Fused: per block (j, n-tile 64): C[64b x 64n] = X_j * exp(pre+off)^T via MFMA, /L
__global__ __launch_bounds__(256, 3) void fused_kernel(
    const unsigned short* __restrict__ xT,  // [J][B*SEQ] bf16
    const float* __restrict__ off,          // [J][SEQ][SEQ]
    const float* __restrict__ pre,          // [SEQ][SEQ]
    float* __restrict__ outT) {             // [J][SEQ][B]
  __shared__ unsigned short As[BATCH * LDB];  // [b][k] k-contiguous
  __shared__ unsigned short Bs[TN * LDB];     // [n][k] k-contiguous
  __shared__ float Lred[TN * 17];
  __shared__ float Linv[TN];

  const int j  = blockIdx.x % JDIM;
  const int n0 = (blockIdx.x / JDIM) * TN;

  const int tid  = threadIdx.x;
  const int lane = tid & 63;
  const int wid  = tid >> 6;      // 4 waves
  const int ln   = lane & 15;
  const int quad = lane >> 4;
  const int bw   = (wid & 1) * 32;  // wave's b-quadrant
  const int nw   = (wid >> 1) * 32; // wave's n-quadrant

  f32x4 acc[2][2];
#pragma unroll
  for (int i = 0; i < 2; ++i)
#pragma unroll
    for (int q = 0; q < 2; ++q) acc[i][q] = (f32x4){0.f, 0.f, 0.f, 0.f};
  float Lpart[4] = {0.f, 0.f, 0.f, 0.f};

  const unsigned short* xTj = xT + (size_t)j * (BATCH * SEQ);
  const float* offj = off + (size_t)j * (SEQ * SEQ);

  const int a_kg = tid & 7;    // 8 groups x 8 bf16 = one row of KC
  const int a_b  = tid >> 3;   // 0..31 (+32)
  const int b_mg = tid & 15;   // float4 group
  const int b_n  = tid >> 4;   // 0..15 (4 passes)

  for (int ch = 0; ch < SEQ / KC; ++ch) {
    const int m0 = ch * KC;
    // stage A: As[b][k] = xTj[b*SEQ + m0 + k]  (16B loads, 16B LDS writes)
#pragma unroll
    for (int p = 0; p < 2; ++p) {
      const int b = a_b + 32 * p;
      uint4 v = *(const uint4*)(xTj + (size_t)b * SEQ + m0 + 8 * a_kg);
      *(uint4*)(&As[b * LDB + 8 * a_kg]) = v;
    }
    // stage B: Bs[n][k] = bf16(exp(off+pre)); fp32 row-sum partials in regs
#pragma unroll
    for (int p = 0; p < 4; ++p) {
      const int nl = b_n + 16 * p;
      const float4 o  = *(const float4*)(offj + (size_t)(n0 + nl) * SEQ + m0 + 4 * b_mg);
      const float4 pr = *(const float4*)(pre  + (size_t)(n0 + nl) * SEQ + m0 + 4 * b_mg);
      const float e0 = __expf(o.x + pr.x);
      const float e1 = __expf(o.y + pr.y);
      const float e2 = __expf(o.z + pr.z);
      const float e3 = __expf(o.w + pr.w);
      Lpart[p] += (e0 + e1) + (e2 + e3);
      uint2 pk;
      pk.x = (unsigned)f2bf(e0) | ((unsigned)f2bf(e1) << 16);
      pk.y = (unsigned)f2bf(e2) | ((unsigned)f2bf(e3) << 16);
      *(uint2*)(&Bs[nl * LDB + 4 * b_mg]) = pk;
    }
    __syncthreads();
    // MFMA: wave computes 32x32 quadrant as 2x2 frags of 16x16
#pragma unroll
    for (int ks = 0; ks < KC; ks += 32) {
      bf16x8 afrag[2], bfrag[2];
#pragma unroll
      for (int i = 0; i < 2; ++i)
        afrag[i] = *(const bf16x8*)(&As[(bw + 16 * i + ln) * LDB + ks + 8 * quad]);
#pragma unroll
      for (int q = 0; q < 2; ++q)
        bfrag[q] = *(const bf16x8*)(&Bs[(nw + 16 * q + ln) * LDB + ks + 8 * quad]);
#pragma unroll
      for (int i = 0; i < 2; ++i)
#pragma unroll
        for (int q = 0; q < 2; ++q)
          acc[i][q] = __builtin_amdgcn_mfma_f32_16x16x32_bf16(afrag[i], bfrag[q], acc[i][q], 0, 0, 0);
    }
    __syncthreads();
  }

  // reduce L across the 16 m-group partials per row
#pragma unroll
  for (int p = 0; p < 4; ++p) Lred[(b_n + 16 * p) * 17 + b_mg] = Lpart[p];
  __syncthreads();
  if (tid < TN) {
    float s = 0.f;
#pragma unroll
    for (int i = 0; i < 16; ++i) s += Lred[tid * 17 + i];
    Linv[tid] = 1.0f / s;
  }
  __syncthreads();

  // epilogue: C/D layout col(=n)=lane&15, row(=b)=quad*4+reg -> float4 along b
  float* outTj = outT + (size_t)j * (SEQ * BATCH);
#pragma unroll
  for (int q = 0; q < 2; ++q) {
    const int nc = nw + 16 * q + ln;
    const float linv = Linv[nc];
#pragma unroll
    for (int i = 0; i < 2; ++i) {
      float4 v;
      v.x = acc[i][q][0] * linv;
      v.y = acc[i][q][1] * linv;
      v.z = acc[i][q][2] * linv;
      v.w = acc[i][q][3] * linv;
      *(float4*)(&outTj[(size_t)(n0 + nc) * BATCH + bw + 16 * i + 4 * quad]) = v;
    }
  }
}

// ---------------- T2: out[b][n][j] = outT[j][n][b]
__global__ __launch_bounds__(256) void transpose_out_kernel(
    const float* __restrict__ outT, float* __restrict__ out) {
  __shared__ float tile[JDIM * 65];  // [j][b]
  const int n = blockIdx.x;          // 512 blocks
  for (int idx = threadIdx.x; idx < JDIM * BATCH; idx += 256) {
    int j = idx >> 6, b = idx & 63;                   // b fastest -> coalesced read
    tile[j * 65 + b] = outT[((size_t)j * SEQ + n) * BATCH + b];
  }
  __syncthreads();
  for (int idx = threadIdx.x; idx < JDIM * BATCH; idx += 256) {
    int b = idx / JDIM, j = idx - b * JDIM;           // j fastest -> coalesced write
    out[((size_t)b * SEQ + n) * JDIM + j] = tile[j * 65 + b];
  }
}

extern "C" void kernel_launch(void* const* d_in, const int* in_sizes, int n_in,
                              void* d_out, int out_size, void* d_ws, size_t ws_size,
                              hipStream_t stream) {
  const float* x   = (const float*)d_in[0];  // [64, 512, 96]
  const float* off = (const float*)d_in[1];  // [96, 512, 512]
  const float* pre = (const float*)d_in[2];  // [512, 512]
  float* out = (float*)d_out;                // [64, 512, 96]

  unsigned short* xT = (unsigned short*)d_ws;                 // bf16 [96][64*512] = 6.29 MB
  float* outT = (float*)((char*)d_ws + (size_t)JDIM * BATCH * SEQ * sizeof(unsigned short));
                                                              // f32 [96][512][64] = 12.58 MB

  transpose_in_kernel<<<BATCH * SEQ / 64, 256, 0, stream>>>(x, xT);
  fused_kernel<<<JDIM * (SEQ / TN), 256, 0, stream>>>(xT, off, pre, outT);
  transpose_out_kernel<<<SEQ, 256, 0, stream>>>(outT, out);
}